// Round 7
// baseline (722.833 us; speedup 1.0000x reference)
//
#include <hip/hip_runtime.h>
#include <hip/hip_cooperative_groups.h>
#include <hip/hip_bf16.h>

namespace cg = cooperative_groups;

#define N_NODES 40000
#define N_EDGES 640000

typedef __attribute__((ext_vector_type(8))) short bfrag;   // 8 bf16
typedef __attribute__((ext_vector_type(4))) float ffrag;   // 4 fp32 acc

__device__ __forceinline__ float b2f(unsigned short u) {
    unsigned int x = ((unsigned int)u) << 16;
    return __builtin_bit_cast(float, x);
}
__device__ __forceinline__ unsigned short f2b(float f) {
    return __builtin_bit_cast(unsigned short, __float2bfloat16(f));
}

// ---------------- shared device helpers ----------------

// CSR scatter, D=64, bf16 in. One wave per node (stride loop); 4 sub-groups of
// 16 lanes take interleaved edges; lane owns 4 cols (ushort4 = 8B loads).
template<bool OUT_F32>
__device__ __forceinline__ void scatter_dev(const unsigned short* __restrict__ T,
                                            const int* __restrict__ srcE,
                                            const int* __restrict__ rowptr,
                                            void* __restrict__ Hv,
                                            int waveGid, int nWaves, int lane) {
    const int sub = lane >> 4;           // 0..3
    const int c4  = (lane & 15) * 4;     // cols c4..c4+3

    for (int node = waveGid; node < N_NODES; node += nWaves) {
        const int e0 = rowptr[node], e1 = rowptr[node + 1];
        float a0 = 0.f, a1 = 0.f, a2 = 0.f, a3 = 0.f;
        int e = e0;
        for (; e + 16 <= e1; e += 16) {
            int sA = srcE[e + 0  + sub];
            int sB = srcE[e + 4  + sub];
            int sC = srcE[e + 8  + sub];
            int sD = srcE[e + 12 + sub];
            ushort4 tA = *(const ushort4*)(T + (size_t)sA * 64 + c4);
            ushort4 tB = *(const ushort4*)(T + (size_t)sB * 64 + c4);
            ushort4 tC = *(const ushort4*)(T + (size_t)sC * 64 + c4);
            ushort4 tD = *(const ushort4*)(T + (size_t)sD * 64 + c4);
            a0 += b2f(tA.x) + b2f(tB.x) + b2f(tC.x) + b2f(tD.x);
            a1 += b2f(tA.y) + b2f(tB.y) + b2f(tC.y) + b2f(tD.y);
            a2 += b2f(tA.z) + b2f(tB.z) + b2f(tC.z) + b2f(tD.z);
            a3 += b2f(tA.w) + b2f(tB.w) + b2f(tC.w) + b2f(tD.w);
        }
        for (; e + 4 <= e1; e += 4) {
            int s = srcE[e + sub];
            ushort4 t = *(const ushort4*)(T + (size_t)s * 64 + c4);
            a0 += b2f(t.x); a1 += b2f(t.y); a2 += b2f(t.z); a3 += b2f(t.w);
        }
        if (e + sub < e1) {
            int s = srcE[e + sub];
            ushort4 t = *(const ushort4*)(T + (size_t)s * 64 + c4);
            a0 += b2f(t.x); a1 += b2f(t.y); a2 += b2f(t.z); a3 += b2f(t.w);
        }

        a0 += __shfl_xor(a0, 16); a0 += __shfl_xor(a0, 32);
        a1 += __shfl_xor(a1, 16); a1 += __shfl_xor(a1, 32);
        a2 += __shfl_xor(a2, 16); a2 += __shfl_xor(a2, 32);
        a3 += __shfl_xor(a3, 16); a3 += __shfl_xor(a3, 32);

        if (sub == 0) {
            if constexpr (OUT_F32) {
                *(float4*)((float*)Hv + (size_t)node * 64 + c4) =
                    make_float4(a0, a1, a2, a3);
            } else {
                ushort4 o;
                o.x = f2b(a0); o.y = f2b(a1); o.z = f2b(a2); o.w = f2b(a3);
                *(ushort4*)((unsigned short*)Hv + (size_t)node * 64 + c4) = o;
            }
        }
    }
}

// MFMA tile: 64 rows of T = bf16(feat @ W123) per tile index.
__device__ __forceinline__ void gemm_tile_dev(const float* __restrict__ X,
                                              const unsigned short* __restrict__ Wt,
                                              unsigned short* __restrict__ Y,
                                              int tile, int wv, int lane) {
    const int ml   = lane & 15;
    const int quad = lane >> 4;
    const int row0 = tile * 64 + wv * 16;

    ffrag acc[4];
#pragma unroll
    for (int c = 0; c < 4; c++) acc[c] = (ffrag)0.f;

#pragma unroll
    for (int kb = 0; kb < 128; kb += 32) {
        const float* p = X + (size_t)(row0 + ml) * 128 + kb + quad * 8;
        float4 u0 = *(const float4*)p;
        float4 u1 = *(const float4*)(p + 4);
        bfrag a;
        a[0] = (short)f2b(u0.x); a[1] = (short)f2b(u0.y);
        a[2] = (short)f2b(u0.z); a[3] = (short)f2b(u0.w);
        a[4] = (short)f2b(u1.x); a[5] = (short)f2b(u1.y);
        a[6] = (short)f2b(u1.z); a[7] = (short)f2b(u1.w);
#pragma unroll
        for (int c = 0; c < 4; c++) {
            const int n = c * 16 + ml;
            bfrag b = *(const bfrag*)(Wt + (size_t)n * 128 + kb + quad * 8);
            acc[c] = __builtin_amdgcn_mfma_f32_16x16x32_bf16(a, b, acc[c], 0, 0, 0);
        }
    }
#pragma unroll
    for (int c = 0; c < 4; c++)
#pragma unroll
        for (int i = 0; i < 4; i++) {
            const int row = row0 + quad * 4 + i;
            const int col = c * 16 + ml;
            Y[(size_t)row * 64 + col] = f2b(acc[c][i]);
        }
}

// ---------------- fused cooperative kernel ----------------
// out = S^3 . (X @ (W1 W2 W3)); S = segment-sum (commutes with W, no
// nonlinearity). All phases grid-stride (any grid size is correct); phases
// separated by device fence + grid.sync(); each buffer written in one phase.
__global__ __launch_bounds__(256, 4) void fused(
        const int* __restrict__ src, const int* __restrict__ dst,
        const float* __restrict__ feat,
        const float* __restrict__ W1, const float* __restrict__ W2,
        const float* __restrict__ W3,
        float* __restrict__ out,
        unsigned short* __restrict__ T, unsigned short* __restrict__ H,
        unsigned short* __restrict__ H2,
        int* __restrict__ rowptr, float* __restrict__ W23,
        unsigned short* __restrict__ Wt123) {
    cg::grid_group grid = cg::this_grid();
    const int tid     = threadIdx.x;
    const int gtid    = blockIdx.x * 256 + tid;
    const int gtotal  = gridDim.x * 256;
    const int lane    = tid & 63;
    const int wv      = tid >> 6;
    const int waveGid = blockIdx.x * 4 + wv;
    const int nWaves  = gridDim.x * 4;

    // ---- Phase 0: rowptr lower_bound + W23 = W2 @ W3 (grid-stride) ----
    for (int i = gtid; i < (N_NODES + 1) + 8192; i += gtotal) {
        if (i <= N_NODES) {
            int lo = 0, hi = N_EDGES;
            while (lo < hi) {
                int mid = (lo + hi) >> 1;
                if (dst[mid] < i) lo = mid + 1; else hi = mid;
            }
            rowptr[i] = lo;
        } else {
            int t = i - (N_NODES + 1);
            int k = t >> 6, n = t & 63;
            float acc = 0.f;
            for (int j = 0; j < 128; j++) acc += W2[k * 128 + j] * W3[j * 64 + n];
            W23[k * 64 + n] = acc;
        }
    }
    __threadfence();
    grid.sync();

    // ---- Phase 1: Wt123[n][k] = bf16( (W1 @ W23)[k][n] ) ----
    for (int i = gtid; i < 8192; i += gtotal) {
        int k = i >> 6, n = i & 63;
        float acc = 0.f;
        for (int j = 0; j < 128; j++) acc += W1[k * 128 + j] * W23[j * 64 + n];
        Wt123[n * 128 + k] = f2b(acc);
    }
    __threadfence();
    grid.sync();

    // ---- Phase 2: T = bf16( feat @ W123 ), MFMA, no LDS ----
    for (int tile = blockIdx.x; tile < N_NODES / 64; tile += gridDim.x)
        gemm_tile_dev(feat, Wt123, T, tile, wv, lane);
    __threadfence();
    grid.sync();

    // ---- Phase 3..5: three segment-sum passes ----
    scatter_dev<false>(T, src, rowptr, H, waveGid, nWaves, lane);
    __threadfence();
    grid.sync();

    scatter_dev<false>(H, src, rowptr, H2, waveGid, nWaves, lane);
    __threadfence();
    grid.sync();

    scatter_dev<true>(H2, src, rowptr, out, waveGid, nWaves, lane);
}

// ---------------- fallback multi-kernel path (proven R5) ----------------
__global__ __launch_bounds__(256) void prepA(const int* __restrict__ dst,
                                             int* __restrict__ rowptr,
                                             const float* __restrict__ W2,
                                             const float* __restrict__ W3,
                                             float* __restrict__ W23) {
    int bid = blockIdx.x;
    if (bid < 157) {
        int n = bid * 256 + threadIdx.x;
        if (n > N_NODES) return;
        int lo = 0, hi = N_EDGES;
        while (lo < hi) {
            int mid = (lo + hi) >> 1;
            if (dst[mid] < n) lo = mid + 1; else hi = mid;
        }
        rowptr[n] = lo;
    } else {
        int t = (bid - 157) * 256 + threadIdx.x;   // 0..1023
        int k  = t >> 3;
        int n0 = (t & 7) * 8;
        float acc[8];
#pragma unroll
        for (int r = 0; r < 8; r++) acc[r] = 0.f;
        for (int j = 0; j < 128; j++) {
            float w2 = W2[k * 128 + j];
#pragma unroll
            for (int r = 0; r < 8; r++) acc[r] += w2 * W3[j * 64 + n0 + r];
        }
#pragma unroll
        for (int r = 0; r < 8; r++) W23[k * 64 + n0 + r] = acc[r];
    }
}

__global__ __launch_bounds__(256) void prepB(const float* __restrict__ W1,
                                             const float* __restrict__ W23,
                                             unsigned short* __restrict__ Wt123) {
    int t  = blockIdx.x * 256 + threadIdx.x;   // 0..1023
    int n  = t >> 4;
    int k0 = (t & 15) * 8;
    float acc[8];
#pragma unroll
    for (int r = 0; r < 8; r++) acc[r] = 0.f;
    for (int j = 0; j < 128; j++) {
        float w23 = W23[j * 64 + n];
#pragma unroll
        for (int r = 0; r < 8; r++) acc[r] += W1[(k0 + r) * 128 + j] * w23;
    }
#pragma unroll
    for (int r = 0; r < 8; r++) Wt123[n * 128 + k0 + r] = f2b(acc[r]);
}

__global__ __launch_bounds__(256) void gemm_mfma64(const float* __restrict__ X,
                                                   const unsigned short* __restrict__ Wt,
                                                   unsigned short* __restrict__ Y) {
    gemm_tile_dev(X, Wt, Y, blockIdx.x, threadIdx.x >> 6, threadIdx.x & 63);
}

template<bool OUT_F32>
__global__ __launch_bounds__(256) void scatter64(const unsigned short* __restrict__ T,
                                                 const int* __restrict__ srcE,
                                                 const int* __restrict__ rowptr,
                                                 void* __restrict__ Hv) {
    const int waveGid = blockIdx.x * 4 + (threadIdx.x >> 6);
    scatter_dev<OUT_F32>(T, srcE, rowptr, Hv, waveGid, 1 << 30, threadIdx.x & 63);
}

extern "C" void kernel_launch(void* const* d_in, const int* in_sizes, int n_in,
                              void* d_out, int out_size, void* d_ws, size_t ws_size,
                              hipStream_t stream) {
    const int*   src  = (const int*)d_in[0];
    const int*   dst  = (const int*)d_in[1];
    const float* feat = (const float*)d_in[2];
    const float* W1   = (const float*)d_in[3];
    const float* W2   = (const float*)d_in[4];
    const float* W3   = (const float*)d_in[5];
    float* out = (float*)d_out;

    // ws layout (bytes): T@0, H@5.25M, H2@10.5M, rowptr@15.75M, W23, Wt123.
    char* wsb = (char*)d_ws;
    unsigned short* T  = (unsigned short*)wsb;
    unsigned short* H  = (unsigned short*)(wsb + (size_t)5505024);
    unsigned short* H2 = (unsigned short*)(wsb + (size_t)11010048);
    int* rowptr        = (int*)(wsb + (size_t)16515072);
    float* W23         = (float*)(wsb + (size_t)16515072 + 163840);
    unsigned short* Wt123 = (unsigned short*)((char*)W23 + 32768);

    // Size the cooperative grid from the driver's own occupancy answer.
    int maxBlkPerCU = 0;
    hipError_t occ_err = hipOccupancyMaxActiveBlocksPerMultiprocessor(
        &maxBlkPerCU, fused, 256, 0);

    hipError_t launch_err = hipErrorUnknown;
    if (occ_err == hipSuccess && maxBlkPerCU > 0) {
        int grid = maxBlkPerCU * 256;          // 256 CUs on MI355X
        if (grid > 1024) grid = 1024;
        void* args[] = { (void*)&src, (void*)&dst, (void*)&feat,
                         (void*)&W1, (void*)&W2, (void*)&W3,
                         (void*)&out, (void*)&T, (void*)&H, (void*)&H2,
                         (void*)&rowptr, (void*)&W23, (void*)&Wt123 };
        launch_err = hipLaunchCooperativeKernel((const void*)fused,
                                                dim3(grid), dim3(256),
                                                args, 0, stream);
    }

    if (launch_err != hipSuccess) {
        // Fallback: proven multi-kernel path (identical math).
        const int scatterBlocks = (N_NODES + 3) / 4;   // 10000
        prepA<<<161, 256, 0, stream>>>(dst, rowptr, W2, W3, W23);
        prepB<<<4, 256, 0, stream>>>(W1, W23, Wt123);
        gemm_mfma64<<<625, 256, 0, stream>>>(feat, Wt123, T);
        scatter64<false><<<scatterBlocks, 256, 0, stream>>>(T, src, rowptr, H);
        scatter64<false><<<scatterBlocks, 256, 0, stream>>>(H, src, rowptr, T);
        scatter64<true><<<scatterBlocks, 256, 0, stream>>>(T, src, rowptr, out);
    }
}

// Round 8
// 234.990 us; speedup vs baseline: 3.0760x; 3.0760x over previous
//
#include <hip/hip_runtime.h>
#include <hip/hip_bf16.h>

#define N_NODES 40000
#define N_EDGES 640000

typedef __attribute__((ext_vector_type(8))) short bfrag;   // 8 bf16
typedef __attribute__((ext_vector_type(4))) float ffrag;   // 4 fp32 acc

__device__ __forceinline__ float b2f_lo(unsigned u) {
    return __builtin_bit_cast(float, u << 16);
}
__device__ __forceinline__ float b2f_hi(unsigned u) {
    return __builtin_bit_cast(float, u & 0xffff0000u);
}
__device__ __forceinline__ unsigned short f2b(float f) {
    return __builtin_bit_cast(unsigned short, __float2bfloat16(f));
}

// ---------------- prep: rowptr (O(E) adjacent-diff) + Wt123 ----------------
// blocks [0, 2657): rowptr boundaries.  blocks [2657, 2665): W123 (8 blocks,
// each computes W23 = W2@W3 into LDS redundantly, then 16 k-rows of Wt123).
#define RP_BLOCKS 2657
__global__ __launch_bounds__(256) void prep(const int* __restrict__ dst,
                                            int* __restrict__ rowptr,
                                            const float* __restrict__ W1,
                                            const float* __restrict__ W2,
                                            const float* __restrict__ W3,
                                            unsigned short* __restrict__ Wt123) {
    __shared__ float W23s[128 * 64];   // 32 KB
    const int bid = blockIdx.x;
    if (bid < RP_BLOCKS) {
        int i = bid * 256 + threadIdx.x;
        if (i < N_EDGES) {
            // boundary between edge i-1 and i: nodes in (dst[i-1], dst[i]] start at i
            int de = dst[i];
            int dp = (i == 0) ? -1 : dst[i - 1];
            for (int n = dp + 1; n <= de; n++) rowptr[n] = i;
        } else if (i < N_EDGES + N_NODES + 1) {
            int n = i - N_EDGES;               // 0..N_NODES
            if (n > dst[N_EDGES - 1]) rowptr[n] = N_EDGES;
        }
        return;
    }

    // ---- W123 part ----
    const int wblk = bid - RP_BLOCKS;          // 0..7
    // phase 1: W23[k][n] = sum_j W2[k][j] * W3[j][n]  (redundant per block)
    for (int idx = threadIdx.x; idx < 8192; idx += 256) {
        int k = idx >> 6, n = idx & 63;
        float acc = 0.f;
        for (int j = 0; j < 128; j++) acc += W2[k * 128 + j] * W3[j * 64 + n];
        W23s[idx] = acc;
    }
    __syncthreads();
    // phase 2: Wt123[n][k] = bf16( sum_j W1[k][j] * W23[j][n] ), k in 16-row slice
    const int n  = threadIdx.x & 63;
    const int kk = threadIdx.x >> 6;           // 0..3
#pragma unroll
    for (int i = 0; i < 4; i++) {
        int k = wblk * 16 + kk * 4 + i;
        float acc = 0.f;
        for (int j = 0; j < 128; j++) acc += W1[k * 128 + j] * W23s[j * 64 + n];
        Wt123[n * 128 + k] = f2b(acc);
    }
}

// ---------------- MFMA GEMM: T[N,64] = bf16( X[N,128] @ W123 ) ----------------
// Fragments straight from global (16B contiguous/lane); no LDS. 64 rows/block.
__global__ __launch_bounds__(256) void gemm_mfma64(const float* __restrict__ X,
                                                   const unsigned short* __restrict__ Wt,
                                                   unsigned short* __restrict__ Y) {
    const int wv   = threadIdx.x >> 6;
    const int lane = threadIdx.x & 63;
    const int ml   = lane & 15;
    const int quad = lane >> 4;
    const int row0 = blockIdx.x * 64 + wv * 16;

    ffrag acc[4];
#pragma unroll
    for (int c = 0; c < 4; c++) acc[c] = (ffrag)0.f;

#pragma unroll
    for (int kb = 0; kb < 128; kb += 32) {
        const float* p = X + (size_t)(row0 + ml) * 128 + kb + quad * 8;
        float4 u0 = *(const float4*)p;
        float4 u1 = *(const float4*)(p + 4);
        bfrag a;
        a[0] = (short)f2b(u0.x); a[1] = (short)f2b(u0.y);
        a[2] = (short)f2b(u0.z); a[3] = (short)f2b(u0.w);
        a[4] = (short)f2b(u1.x); a[5] = (short)f2b(u1.y);
        a[6] = (short)f2b(u1.z); a[7] = (short)f2b(u1.w);
#pragma unroll
        for (int c = 0; c < 4; c++) {
            const int col = c * 16 + ml;
            bfrag b = *(const bfrag*)(Wt + (size_t)col * 128 + kb + quad * 8);
            acc[c] = __builtin_amdgcn_mfma_f32_16x16x32_bf16(a, b, acc[c], 0, 0, 0);
        }
    }
#pragma unroll
    for (int c = 0; c < 4; c++)
#pragma unroll
        for (int i = 0; i < 4; i++)
            Y[(size_t)(row0 + quad * 4 + i) * 64 + c * 16 + ml] = f2b(acc[c][i]);
}

// ---------------- CSR scatter v3, D=64, bf16 in ----------------
// 8 nodes per wave (one per 8-lane group); lane owns 8 cols via one 16B uint4
// load (128B/row); unroll-2; no cross-group reduction; contiguous stores.
template<bool OUT_F32>
__global__ __launch_bounds__(256) void scatter8(const unsigned short* __restrict__ T,
                                                const int* __restrict__ srcE,
                                                const int* __restrict__ rowptr,
                                                void* __restrict__ Hv) {
    const int wave = blockIdx.x * 4 + (threadIdx.x >> 6);
    const int lane = threadIdx.x & 63;
    const int g    = lane >> 3;          // group 0..7 -> node
    const int c8   = (lane & 7) * 8;     // cols c8..c8+7
    const int node = wave * 8 + g;
    if (node >= N_NODES) return;
    const int e0 = rowptr[node], e1 = rowptr[node + 1];

    float a0 = 0.f, a1 = 0.f, a2 = 0.f, a3 = 0.f;
    float a4 = 0.f, a5 = 0.f, a6 = 0.f, a7 = 0.f;
    int e = e0;
    for (; e + 2 <= e1; e += 2) {
        int s0 = srcE[e], s1 = srcE[e + 1];
        uint4 t0 = *(const uint4*)(T + (size_t)s0 * 64 + c8);
        uint4 t1 = *(const uint4*)(T + (size_t)s1 * 64 + c8);
        a0 += b2f_lo(t0.x) + b2f_lo(t1.x);
        a1 += b2f_hi(t0.x) + b2f_hi(t1.x);
        a2 += b2f_lo(t0.y) + b2f_lo(t1.y);
        a3 += b2f_hi(t0.y) + b2f_hi(t1.y);
        a4 += b2f_lo(t0.z) + b2f_lo(t1.z);
        a5 += b2f_hi(t0.z) + b2f_hi(t1.z);
        a6 += b2f_lo(t0.w) + b2f_lo(t1.w);
        a7 += b2f_hi(t0.w) + b2f_hi(t1.w);
    }
    if (e < e1) {
        uint4 t0 = *(const uint4*)(T + (size_t)srcE[e] * 64 + c8);
        a0 += b2f_lo(t0.x); a1 += b2f_hi(t0.x);
        a2 += b2f_lo(t0.y); a3 += b2f_hi(t0.y);
        a4 += b2f_lo(t0.z); a5 += b2f_hi(t0.z);
        a6 += b2f_lo(t0.w); a7 += b2f_hi(t0.w);
    }

    if constexpr (OUT_F32) {
        float* q = (float*)Hv + (size_t)node * 64 + c8;
        *(float4*)q       = make_float4(a0, a1, a2, a3);
        *(float4*)(q + 4) = make_float4(a4, a5, a6, a7);
    } else {
        ushort4 o0, o1;
        o0.x = f2b(a0); o0.y = f2b(a1); o0.z = f2b(a2); o0.w = f2b(a3);
        o1.x = f2b(a4); o1.y = f2b(a5); o1.z = f2b(a6); o1.w = f2b(a7);
        unsigned short* q = (unsigned short*)Hv + (size_t)node * 64 + c8;
        *(ushort4*)q       = o0;
        *(ushort4*)(q + 4) = o1;
    }
}

extern "C" void kernel_launch(void* const* d_in, const int* in_sizes, int n_in,
                              void* d_out, int out_size, void* d_ws, size_t ws_size,
                              hipStream_t stream) {
    const int*   src  = (const int*)d_in[0];
    const int*   dst  = (const int*)d_in[1];
    const float* feat = (const float*)d_in[2];
    const float* W1   = (const float*)d_in[3];
    const float* W2   = (const float*)d_in[4];
    const float* W3   = (const float*)d_in[5];
    float* out = (float*)d_out;

    // ws layout (bytes): T@0, H@5.25M, rowptr@10.5M, Wt123 after.
    char* wsb = (char*)d_ws;
    unsigned short* T  = (unsigned short*)wsb;
    unsigned short* H  = (unsigned short*)(wsb + (size_t)5505024);
    int* rowptr        = (int*)(wsb + (size_t)11010048);
    unsigned short* Wt123 = (unsigned short*)(wsb + (size_t)11010048 + 163844 + 60);

    const int scatterBlocks = (N_NODES + 31) / 32;   // 1250 (8 nodes x 4 waves)

    // out = S^3 . (X @ (W1 W2 W3))  — S = segment-sum, commutes with W (no nonlinearity)
    prep<<<RP_BLOCKS + 8, 256, 0, stream>>>(dst, rowptr, W1, W2, W3, Wt123);
    gemm_mfma64<<<625, 256, 0, stream>>>(feat, Wt123, T);
    scatter8<false><<<scatterBlocks, 256, 0, stream>>>(T, src, rowptr, H);
    scatter8<false><<<scatterBlocks, 256, 0, stream>>>(H, src, rowptr, T);
    scatter8<true><<<scatterBlocks, 256, 0, stream>>>(T, src, rowptr, out);
}

// Round 9
// 172.690 us; speedup vs baseline: 4.1857x; 1.3608x over previous
//
#include <hip/hip_runtime.h>
#include <hip/hip_bf16.h>

#define N_NODES 40000
#define N_EDGES 640000

typedef __attribute__((ext_vector_type(8))) short bfrag;   // 8 bf16
typedef __attribute__((ext_vector_type(4))) float ffrag;   // 4 fp32 acc

__device__ __forceinline__ float b2f_lo(unsigned u) {
    return __builtin_bit_cast(float, u << 16);
}
__device__ __forceinline__ float b2f_hi(unsigned u) {
    return __builtin_bit_cast(float, u & 0xffff0000u);
}
__device__ __forceinline__ unsigned short f2b(float f) {
    return __builtin_bit_cast(unsigned short, __float2bfloat16(f));
}

// ---------------- prep1: rowptr (O(E) adjacent-diff) + W23 = W2@W3 ----------------
// blocks [0, RP): rowptr boundaries. blocks [RP, RP+4): W23 fp32, 8-acc ILP.
#define RP_BLOCKS 2657
__global__ __launch_bounds__(256) void prep1(const int* __restrict__ dst,
                                             int* __restrict__ rowptr,
                                             const float* __restrict__ W2,
                                             const float* __restrict__ W3,
                                             float* __restrict__ W23) {
    const int bid = blockIdx.x;
    if (bid < RP_BLOCKS) {
        int i = bid * 256 + threadIdx.x;
        if (i < N_EDGES) {
            // nodes in (dst[i-1], dst[i]] start at edge i
            int de = dst[i];
            int dp = (i == 0) ? -1 : dst[i - 1];
            for (int n = dp + 1; n <= de; n++) rowptr[n] = i;
        } else if (i < N_EDGES + N_NODES + 1) {
            int n = i - N_EDGES;               // 0..N_NODES
            if (n > dst[N_EDGES - 1]) rowptr[n] = N_EDGES;
        }
        return;
    }
    // W23 part: 4 blocks x 256 threads; thread -> k = t>>3, n0 = (t&7)*8; 8 accs.
    int t  = (bid - RP_BLOCKS) * 256 + threadIdx.x;   // 0..1023
    int k  = t >> 3;                                   // 0..127
    int n0 = (t & 7) * 8;                              // 0..56
    float acc[8];
#pragma unroll
    for (int r = 0; r < 8; r++) acc[r] = 0.f;
    for (int j = 0; j < 128; j++) {
        float w2 = W2[k * 128 + j];
#pragma unroll
        for (int r = 0; r < 8; r++) acc[r] += w2 * W3[j * 64 + n0 + r];
    }
#pragma unroll
    for (int r = 0; r < 8; r++) W23[k * 64 + n0 + r] = acc[r];
}

// ---------------- prep2: Wt123[n][k] = bf16( (W1 @ W23)[k][n] ) ----------------
// 4 blocks x 256 threads; thread -> n = t>>4, k0 = (t&15)*8; 8 accs.
__global__ __launch_bounds__(256) void prep2(const float* __restrict__ W1,
                                             const float* __restrict__ W23,
                                             unsigned short* __restrict__ Wt123) {
    int t  = blockIdx.x * 256 + threadIdx.x;   // 0..1023
    int n  = t >> 4;                            // 0..63
    int k0 = (t & 15) * 8;                      // 0..120
    float acc[8];
#pragma unroll
    for (int r = 0; r < 8; r++) acc[r] = 0.f;
    for (int j = 0; j < 128; j++) {
        float w23 = W23[j * 64 + n];
#pragma unroll
        for (int r = 0; r < 8; r++) acc[r] += W1[(k0 + r) * 128 + j] * w23;
    }
#pragma unroll
    for (int r = 0; r < 8; r++) Wt123[n * 128 + k0 + r] = f2b(acc[r]);
}

// ---------------- MFMA GEMM: T[N,64] = bf16( X[N,128] @ W123 ) ----------------
// Fragments straight from global (16B contiguous/lane); no LDS. 64 rows/block.
__global__ __launch_bounds__(256) void gemm_mfma64(const float* __restrict__ X,
                                                   const unsigned short* __restrict__ Wt,
                                                   unsigned short* __restrict__ Y) {
    const int wv   = threadIdx.x >> 6;
    const int lane = threadIdx.x & 63;
    const int ml   = lane & 15;
    const int quad = lane >> 4;
    const int row0 = blockIdx.x * 64 + wv * 16;

    ffrag acc[4];
#pragma unroll
    for (int c = 0; c < 4; c++) acc[c] = (ffrag)0.f;

#pragma unroll
    for (int kb = 0; kb < 128; kb += 32) {
        const float* p = X + (size_t)(row0 + ml) * 128 + kb + quad * 8;
        float4 u0 = *(const float4*)p;
        float4 u1 = *(const float4*)(p + 4);
        bfrag a;
        a[0] = (short)f2b(u0.x); a[1] = (short)f2b(u0.y);
        a[2] = (short)f2b(u0.z); a[3] = (short)f2b(u0.w);
        a[4] = (short)f2b(u1.x); a[5] = (short)f2b(u1.y);
        a[6] = (short)f2b(u1.z); a[7] = (short)f2b(u1.w);
#pragma unroll
        for (int c = 0; c < 4; c++) {
            const int col = c * 16 + ml;
            bfrag b = *(const bfrag*)(Wt + (size_t)col * 128 + kb + quad * 8);
            acc[c] = __builtin_amdgcn_mfma_f32_16x16x32_bf16(a, b, acc[c], 0, 0, 0);
        }
    }
#pragma unroll
    for (int c = 0; c < 4; c++)
#pragma unroll
        for (int i = 0; i < 4; i++)
            Y[(size_t)(row0 + quad * 4 + i) * 64 + c * 16 + ml] = f2b(acc[c][i]);
}

// ---------------- CSR scatter, D=64, bf16 in ----------------
// 8 nodes per wave (one per 8-lane group); lane owns 8 cols via one 16B uint4
// load (128B/row); unroll-2; no cross-group reduction; contiguous stores.
template<bool OUT_F32>
__global__ __launch_bounds__(256) void scatter8(const unsigned short* __restrict__ T,
                                                const int* __restrict__ srcE,
                                                const int* __restrict__ rowptr,
                                                void* __restrict__ Hv) {
    const int wave = blockIdx.x * 4 + (threadIdx.x >> 6);
    const int lane = threadIdx.x & 63;
    const int g    = lane >> 3;          // group 0..7 -> node
    const int c8   = (lane & 7) * 8;     // cols c8..c8+7
    const int node = wave * 8 + g;
    if (node >= N_NODES) return;
    const int e0 = rowptr[node], e1 = rowptr[node + 1];

    float a0 = 0.f, a1 = 0.f, a2 = 0.f, a3 = 0.f;
    float a4 = 0.f, a5 = 0.f, a6 = 0.f, a7 = 0.f;
    int e = e0;
    for (; e + 2 <= e1; e += 2) {
        int s0 = srcE[e], s1 = srcE[e + 1];
        uint4 t0 = *(const uint4*)(T + (size_t)s0 * 64 + c8);
        uint4 t1 = *(const uint4*)(T + (size_t)s1 * 64 + c8);
        a0 += b2f_lo(t0.x) + b2f_lo(t1.x);
        a1 += b2f_hi(t0.x) + b2f_hi(t1.x);
        a2 += b2f_lo(t0.y) + b2f_lo(t1.y);
        a3 += b2f_hi(t0.y) + b2f_hi(t1.y);
        a4 += b2f_lo(t0.z) + b2f_lo(t1.z);
        a5 += b2f_hi(t0.z) + b2f_hi(t1.z);
        a6 += b2f_lo(t0.w) + b2f_lo(t1.w);
        a7 += b2f_hi(t0.w) + b2f_hi(t1.w);
    }
    if (e < e1) {
        uint4 t0 = *(const uint4*)(T + (size_t)srcE[e] * 64 + c8);
        a0 += b2f_lo(t0.x); a1 += b2f_hi(t0.x);
        a2 += b2f_lo(t0.y); a3 += b2f_hi(t0.y);
        a4 += b2f_lo(t0.z); a5 += b2f_hi(t0.z);
        a6 += b2f_lo(t0.w); a7 += b2f_hi(t0.w);
    }

    if constexpr (OUT_F32) {
        float* q = (float*)Hv + (size_t)node * 64 + c8;
        *(float4*)q       = make_float4(a0, a1, a2, a3);
        *(float4*)(q + 4) = make_float4(a4, a5, a6, a7);
    } else {
        ushort4 o0, o1;
        o0.x = f2b(a0); o0.y = f2b(a1); o0.z = f2b(a2); o0.w = f2b(a3);
        o1.x = f2b(a4); o1.y = f2b(a5); o1.z = f2b(a6); o1.w = f2b(a7);
        unsigned short* q = (unsigned short*)Hv + (size_t)node * 64 + c8;
        *(ushort4*)q       = o0;
        *(ushort4*)(q + 4) = o1;
    }
}

extern "C" void kernel_launch(void* const* d_in, const int* in_sizes, int n_in,
                              void* d_out, int out_size, void* d_ws, size_t ws_size,
                              hipStream_t stream) {
    const int*   src  = (const int*)d_in[0];
    const int*   dst  = (const int*)d_in[1];
    const float* feat = (const float*)d_in[2];
    const float* W1   = (const float*)d_in[3];
    const float* W2   = (const float*)d_in[4];
    const float* W3   = (const float*)d_in[5];
    float* out = (float*)d_out;

    // ws layout (bytes): T@0, H@5.25M, rowptr@10.5M, W23 + Wt123 after.
    char* wsb = (char*)d_ws;
    unsigned short* T  = (unsigned short*)wsb;
    unsigned short* H  = (unsigned short*)(wsb + (size_t)5505024);
    int* rowptr        = (int*)(wsb + (size_t)11010048);
    float* W23         = (float*)(wsb + (size_t)11010048 + 163968);
    unsigned short* Wt123 = (unsigned short*)((char*)W23 + 32768);

    const int scatterBlocks = (N_NODES + 31) / 32;   // 1250 (8 nodes x 4 waves)

    // out = S^3 . (X @ (W1 W2 W3))  — S = segment-sum, commutes with W (no nonlinearity)
    prep1<<<RP_BLOCKS + 4, 256, 0, stream>>>(dst, rowptr, W2, W3, W23);
    prep2<<<4, 256, 0, stream>>>(W1, W23, Wt123);
    gemm_mfma64<<<625, 256, 0, stream>>>(feat, Wt123, T);
    scatter8<false><<<scatterBlocks, 256, 0, stream>>>(T, src, rowptr, H);
    scatter8<false><<<scatterBlocks, 256, 0, stream>>>(H, src, rowptr, T);
    scatter8<true><<<scatterBlocks, 256, 0, stream>>>(T, src, rowptr, out);
}